// Round 1
// baseline (275.422 us; speedup 1.0000x reference)
//
#include <hip/hip_runtime.h>
#include <hip/hip_bf16.h>
#include <stdint.h>

#define IN_F   4096
#define OUT_F  4096
#define M_ROWS 2048
#define LORA_SCALE 2.0f   // 32.0 / 16

typedef __bf16 bf16x8 __attribute__((ext_vector_type(8)));
typedef float  f32x4  __attribute__((ext_vector_type(4)));

typedef const __attribute__((address_space(1))) void gvoid_t;
typedef __attribute__((address_space(3))) void lvoid_t;

// s_waitcnt imm: vmcnt[3:0]|[15:14], expcnt[6:4]=7 (nowait), lgkmcnt[11:8]=15 (nowait)
#define WAITVM(n) __builtin_amdgcn_s_waitcnt(((n)&0xF) | (((n)>>4)<<14) | (7<<4) | (15<<8))

// ---------- 1a. dequant W: 4-bit codes (one byte per int32, 2 nibbles) -> bf16
// 8192 blocks x 256 threads, 8 weights/thread. Pure streaming: 33.5R + 33.5W MB.
__global__ void dequant_kernel(const int* __restrict__ qw,
                               const float* __restrict__ scales,
                               __hip_bfloat16* __restrict__ W) {
    int t = blockIdx.x * 256 + threadIdx.x;
    int4 q = ((const int4*)qw)[t];
    float scale = scales[t >> 3];
    float step = scale * (2.0f / 15.0f);
    int bb[4] = {q.x, q.y, q.z, q.w};
    union { __hip_bfloat16 h[8]; uint4 v; } o;
    #pragma unroll
    for (int j = 0; j < 4; ++j) {
        float lo = (float)(bb[j] & 15)        * step - scale;
        float hi = (float)((bb[j] >> 4) & 15) * step - scale;
        o.h[2*j]   = __float2bfloat16(lo);
        o.h[2*j+1] = __float2bfloat16(hi);
    }
    ((uint4*)W)[t] = o.v;
}

// ---------- 1b. x cast f32 -> bf16. 4096 blocks x 256 threads, 8 elems/thread.
// Streaming: 33.5R + 16.8W MB.
__global__ void xcast_kernel(const float* __restrict__ x,
                             __hip_bfloat16* __restrict__ xb) {
    int t = blockIdx.x * 256 + threadIdx.x;
    float4 a = ((const float4*)x)[2*t];
    float4 c = ((const float4*)x)[2*t + 1];
    union { __hip_bfloat16 h[8]; uint4 v; } o;
    o.h[0] = __float2bfloat16(a.x); o.h[1] = __float2bfloat16(a.y);
    o.h[2] = __float2bfloat16(a.z); o.h[3] = __float2bfloat16(a.w);
    o.h[4] = __float2bfloat16(c.x); o.h[5] = __float2bfloat16(c.y);
    o.h[6] = __float2bfloat16(c.z); o.h[7] = __float2bfloat16(c.w);
    ((uint4*)xb)[t] = o.v;
}

// ---------- 1c. lora t = x @ A^T  [2048,16]. 512 blocks x 256 threads,
// 4 rows/block; thread (r,g) covers lora-dim r, k-chunk g of 8 floats.
// 32 iterations, 10 independent float4 loads per iter (2 A + 8 x) for MLP.
__global__ void lora_kernel(const float* __restrict__ x,
                            const float* __restrict__ A,
                            float* __restrict__ tout) {
    __shared__ float red[16 * 4 * 16];
    int m0 = blockIdx.x * 4;
    int r = threadIdx.x & 15;
    int g = threadIdx.x >> 4;
    float acc[4] = {0.f, 0.f, 0.f, 0.f};
    const float* ar = A + (size_t)r * IN_F;
    for (int kb = 0; kb < 32; ++kb) {
        int k = kb * 128 + g * 8;
        float4 a0 = *(const float4*)(ar + k);
        float4 a1 = *(const float4*)(ar + k + 4);
        #pragma unroll
        for (int row = 0; row < 4; ++row) {
            float4 x0 = *(const float4*)(x + (size_t)(m0 + row) * IN_F + k);
            float4 x1 = *(const float4*)(x + (size_t)(m0 + row) * IN_F + k + 4);
            acc[row] += x0.x*a0.x + x0.y*a0.y + x0.z*a0.z + x0.w*a0.w
                      + x1.x*a1.x + x1.y*a1.y + x1.z*a1.z + x1.w*a1.w;
        }
    }
    #pragma unroll
    for (int row = 0; row < 4; ++row) red[g*64 + row*16 + r] = acc[row];
    __syncthreads();
    if (threadIdx.x < 64) {
        int row = threadIdx.x >> 4, rr = threadIdx.x & 15;
        float s = 0.f;
        #pragma unroll
        for (int gg = 0; gg < 16; ++gg) s += red[gg*64 + row*16 + rr];
        tout[(size_t)(m0 + row) * 16 + rr] = s;
    }
}

// ---------- 2. Deep-pipelined GEMM: 4 waves, 128x128 tile, BK=32, 4 LDS stages,
// prefetch distance 3, raw s_barrier (no vmcnt(0) drain) + per-wave partial
// vmcnt waits. DMA target buffer always holds slab i-1 (readers provably done
// before the barrier we just passed) -> no overwrite race (the R9 bug).
// Fused epilogue: out = acc + bias + 2*(t @ loraB^T).
// This round: + s_setprio(1) around the MFMA cluster (T5).
__global__ __launch_bounds__(256) void gemm_kernel(
        const __hip_bfloat16* __restrict__ A,     // [M, K] bf16
        const __hip_bfloat16* __restrict__ B,     // [N, K] bf16 (= W)
        const float* __restrict__ bias,           // [N]
        const float* __restrict__ loraB,          // [N, 16]
        const float* __restrict__ tmat,           // [M, 16]
        float* __restrict__ out) {                // [M, N]
    const int K = IN_F, N = OUT_F;
    __shared__ union alignas(16) {
        struct { __hip_bfloat16 As[4][128*32]; __hip_bfloat16 Bs[4][128*32]; } s; // 64 KB
        float tl[128 * 16];                       // 8 KB, overlaps As[0] only
    } sm;

    int tid  = threadIdx.x;
    int wave = tid >> 6, lane = tid & 63;
    int wm = wave >> 1, wn = wave & 1;            // 2x2 wave grid over 128x128
    int row16 = lane & 15, quad = lane >> 4;
    int m0 = blockIdx.y * 128, n0 = blockIdx.x * 128;

    // DMA mapping (verified R5/R8): lane i -> row rl=i>>2 of 16-row segment,
    // global 16B-chunk cg=(i&3)^((rl>>1)&3); LDS lands at base + lane*16.
    int rl = lane >> 2;
    int cg = (lane & 3) ^ ((rl >> 1) & 3);

    // 4 persistent DMA pointers (A segs wave*2, wave*2+1; same for B)
    const __hip_bfloat16* pA0 = A + (size_t)(m0 + wave*32 + rl) * K + cg*8;
    const __hip_bfloat16* pA1 = pA0 + (size_t)16 * K;
    const __hip_bfloat16* pB0 = B + (size_t)(n0 + wave*32 + rl) * K + cg*8;
    const __hip_bfloat16* pB1 = pB0 + (size_t)16 * K;

    f32x4 acc[4][4];
    #pragma unroll
    for (int i = 0; i < 4; ++i)
        #pragma unroll
        for (int j = 0; j < 4; ++j) acc[i][j] = (f32x4){0.f, 0.f, 0.f, 0.f};

    // stage next slab into stage `buf` (4 loads/wave), advance one slab (64 B)
    #define DMA(buf)                                                              \
        __builtin_amdgcn_global_load_lds((gvoid_t*)pA0, (lvoid_t*)&sm.s.As[buf][(wave*2+0)*512], 16, 0, 0); \
        __builtin_amdgcn_global_load_lds((gvoid_t*)pA1, (lvoid_t*)&sm.s.As[buf][(wave*2+1)*512], 16, 0, 0); \
        __builtin_amdgcn_global_load_lds((gvoid_t*)pB0, (lvoid_t*)&sm.s.Bs[buf][(wave*2+0)*512], 16, 0, 0); \
        __builtin_amdgcn_global_load_lds((gvoid_t*)pB1, (lvoid_t*)&sm.s.Bs[buf][(wave*2+1)*512], 16, 0, 0); \
        pA0 += 32; pA1 += 32; pB0 += 32; pB1 += 32;

    // one 16x16x32 k-step over the slab in stage `buf` (verified R8 math)
    #define COMPUTE(buf)                                                          \
    {                                                                             \
        bf16x8 af[4], bfr[4];                                                     \
        _Pragma("unroll")                                                         \
        for (int mt = 0; mt < 4; ++mt) {                                          \
            int row = wm*64 + mt*16 + row16;                                      \
            af[mt] = *(const bf16x8*)&sm.s.As[buf][row*32 + ((quad ^ ((row>>1)&3)) << 3)]; \
        }                                                                         \
        _Pragma("unroll")                                                         \
        for (int nt = 0; nt < 4; ++nt) {                                          \
            int row = wn*64 + nt*16 + row16;                                      \
            bfr[nt] = *(const bf16x8*)&sm.s.Bs[buf][row*32 + ((quad ^ ((row>>1)&3)) << 3)]; \
        }                                                                         \
        __builtin_amdgcn_s_setprio(1);                                            \
        _Pragma("unroll")                                                         \
        for (int mt = 0; mt < 4; ++mt)                                            \
            _Pragma("unroll")                                                     \
            for (int nt = 0; nt < 4; ++nt)                                        \
                acc[mt][nt] = __builtin_amdgcn_mfma_f32_16x16x32_bf16(            \
                    af[mt], bfr[nt], acc[mt][nt], 0, 0, 0);                       \
        __builtin_amdgcn_s_setprio(0);                                            \
    }

    // one pipeline step: consume slab in stage p, prefetch into stage (p+3)&3
    // (which holds slab i-1: all waves' reads of it completed before the
    // s_barrier we just passed -> safe to overwrite)
    #define STEP(p)                                                               \
        WAITVM(8);                         /* own slab-i loads retired */         \
        __builtin_amdgcn_s_barrier();      /* all waves ditto => slab i in LDS */ \
        __builtin_amdgcn_sched_barrier(0);                                        \
        COMPUTE(p)                                                                \
        DMA((p+3)&3)

    // prologue: slabs 0,1,2 -> stages 0,1,2 (12 loads/wave outstanding)
    DMA(0)
    DMA(1)
    DMA(2)

    // main: groups u=0..30 consume slabs 4u..4u+3, prefetch 4u+3..4u+6
    for (int u = 0; u < 31; ++u) {
        STEP(0)
        STEP(1)
        STEP(2)
        STEP(3)
    }
    // tail: slabs 124..127 (slab 127 issued at p=0; then drain)
    STEP(0)
    WAITVM(8); __builtin_amdgcn_s_barrier(); __builtin_amdgcn_sched_barrier(0);
    COMPUTE(1)
    WAITVM(4); __builtin_amdgcn_s_barrier(); __builtin_amdgcn_sched_barrier(0);
    COMPUTE(2)
    WAITVM(0); __builtin_amdgcn_s_barrier(); __builtin_amdgcn_sched_barrier(0);
    COMPUTE(3)

    #undef STEP
    #undef COMPUTE
    #undef DMA

    // fused epilogue. tl overlaps As[0] (all stage reads are complete: each
    // wave's last ds_reads finished before its final barrier/MFMA waits; only
    // Bs[3]/As[3] are possibly still being read, and tl is disjoint from them).
    #pragma unroll
    for (int i = 0; i < 2; ++i)
        ((float4*)sm.tl)[tid + i*256] =
            ((const float4*)(tmat + (size_t)m0 * 16))[tid + i*256];
    __syncthreads();

    #pragma unroll
    for (int nt = 0; nt < 4; ++nt) {
        int n = n0 + wn*64 + nt*16 + row16;
        float bn = bias[n];
        const float4* lb = (const float4*)(loraB + (size_t)n * 16);
        float4 b0 = lb[0], b1 = lb[1], b2 = lb[2], b3 = lb[3];
        #pragma unroll
        for (int mt = 0; mt < 4; ++mt) {
            #pragma unroll
            for (int r = 0; r < 4; ++r) {
                int ml = wm*64 + mt*16 + quad*4 + r;
                const float* tm = &sm.tl[ml * 16];
                float dot =
                    tm[0]*b0.x + tm[1]*b0.y + tm[2]*b0.z + tm[3]*b0.w +
                    tm[4]*b1.x + tm[5]*b1.y + tm[6]*b1.z + tm[7]*b1.w +
                    tm[8]*b2.x + tm[9]*b2.y + tm[10]*b2.z + tm[11]*b2.w +
                    tm[12]*b3.x + tm[13]*b3.y + tm[14]*b3.z + tm[15]*b3.w;
                out[(size_t)(m0 + ml) * N + n] = acc[mt][nt][r] + bn + LORA_SCALE * dot;
            }
        }
    }
}

extern "C" void kernel_launch(void* const* d_in, const int* in_sizes, int n_in,
                              void* d_out, int out_size, void* d_ws, size_t ws_size,
                              hipStream_t stream) {
    const float* x      = (const float*)d_in[0];   // [2,1024,4096]
    const int*   qw     = (const int*)d_in[1];     // [8388608] one byte each
    const float* scales = (const float*)d_in[2];   // [262144]
    const float* bias   = (const float*)d_in[3];   // [4096]
    const float* loraA  = (const float*)d_in[4];   // [16,4096]
    const float* loraB  = (const float*)d_in[5];   // [4096,16]
    float* out = (float*)d_out;

    char* ws = (char*)d_ws;
    __hip_bfloat16* Wb = (__hip_bfloat16*)ws;                 // 33,554,432 B
    __hip_bfloat16* Xb = (__hip_bfloat16*)(ws + 33554432);    // 16,777,216 B
    float* tmat        = (float*)(ws + 50331648);             //    131,072 B

    dequant_kernel<<<8192, 256, 0, stream>>>(qw, scales, Wb);
    xcast_kernel<<<4096, 256, 0, stream>>>(x, Xb);
    lora_kernel<<<512, 256, 0, stream>>>(x, loraA, tmat);
    gemm_kernel<<<dim3(32, 16), 256, 0, stream>>>(Xb, Wb, bias, loraB, tmat, out);
}

// Round 4
// 271.800 us; speedup vs baseline: 1.0133x; 1.0133x over previous
//
#include <hip/hip_runtime.h>
#include <hip/hip_bf16.h>
#include <stdint.h>

#define IN_F   4096
#define OUT_F  4096
#define M_ROWS 2048
#define LORA_SCALE 2.0f   // 32.0 / 16

typedef __bf16 bf16x8 __attribute__((ext_vector_type(8)));
typedef float  f32x4  __attribute__((ext_vector_type(4)));

typedef const __attribute__((address_space(1))) void gvoid_t;
typedef __attribute__((address_space(3))) void lvoid_t;

// s_waitcnt imm: vmcnt[3:0]|[15:14], expcnt[6:4]=7 (nowait), lgkmcnt[11:8]=15 (nowait)
#define WAITVM(n) __builtin_amdgcn_s_waitcnt(((n)&0xF) | (((n)>>4)<<14) | (7<<4) | (15<<8))

// ---------- 1a. dequant W: 4-bit codes (one byte per int32, 2 nibbles) -> bf16
// 8192 blocks x 256 threads, 8 weights/thread. Pure streaming: 33.5R + 33.5W MB.
// [ran R1]
__global__ void dequant_kernel(const int* __restrict__ qw,
                               const float* __restrict__ scales,
                               __hip_bfloat16* __restrict__ W) {
    int t = blockIdx.x * 256 + threadIdx.x;
    int4 q = ((const int4*)qw)[t];
    float scale = scales[t >> 3];
    float step = scale * (2.0f / 15.0f);
    int bb[4] = {q.x, q.y, q.z, q.w};
    union { __hip_bfloat16 h[8]; uint4 v; } o;
    #pragma unroll
    for (int j = 0; j < 4; ++j) {
        float lo = (float)(bb[j] & 15)        * step - scale;
        float hi = (float)((bb[j] >> 4) & 15) * step - scale;
        o.h[2*j]   = __float2bfloat16(lo);
        o.h[2*j+1] = __float2bfloat16(hi);
    }
    ((uint4*)W)[t] = o.v;
}

// ---------- 1b. x cast f32 -> bf16. 4096 blocks x 256 threads, 8 elems/thread.
// Streaming: 33.5R + 16.8W MB. [ran R1]
__global__ void xcast_kernel(const float* __restrict__ x,
                             __hip_bfloat16* __restrict__ xb) {
    int t = blockIdx.x * 256 + threadIdx.x;
    float4 a = ((const float4*)x)[2*t];
    float4 c = ((const float4*)x)[2*t + 1];
    union { __hip_bfloat16 h[8]; uint4 v; } o;
    o.h[0] = __float2bfloat16(a.x); o.h[1] = __float2bfloat16(a.y);
    o.h[2] = __float2bfloat16(a.z); o.h[3] = __float2bfloat16(a.w);
    o.h[4] = __float2bfloat16(c.x); o.h[5] = __float2bfloat16(c.y);
    o.h[6] = __float2bfloat16(c.z); o.h[7] = __float2bfloat16(c.w);
    ((uint4*)xb)[t] = o.v;
}

// ---------- 1c. lora t = x @ A^T  [2048,16]. 512 blocks x 256 threads,
// 4 rows/block; thread (r,g) covers lora-dim r, k-chunk g of 8 floats. [ran R1]
__global__ void lora_kernel(const float* __restrict__ x,
                            const float* __restrict__ A,
                            float* __restrict__ tout) {
    __shared__ float red[16 * 4 * 16];
    int m0 = blockIdx.x * 4;
    int r = threadIdx.x & 15;
    int g = threadIdx.x >> 4;
    float acc[4] = {0.f, 0.f, 0.f, 0.f};
    const float* ar = A + (size_t)r * IN_F;
    for (int kb = 0; kb < 32; ++kb) {
        int k = kb * 128 + g * 8;
        float4 a0 = *(const float4*)(ar + k);
        float4 a1 = *(const float4*)(ar + k + 4);
        #pragma unroll
        for (int row = 0; row < 4; ++row) {
            float4 x0 = *(const float4*)(x + (size_t)(m0 + row) * IN_F + k);
            float4 x1 = *(const float4*)(x + (size_t)(m0 + row) * IN_F + k + 4);
            acc[row] += x0.x*a0.x + x0.y*a0.y + x0.z*a0.z + x0.w*a0.w
                      + x1.x*a1.x + x1.y*a1.y + x1.z*a1.z + x1.w*a1.w;
        }
    }
    #pragma unroll
    for (int row = 0; row < 4; ++row) red[g*64 + row*16 + r] = acc[row];
    __syncthreads();
    if (threadIdx.x < 64) {
        int row = threadIdx.x >> 4, rr = threadIdx.x & 15;
        float s = 0.f;
        #pragma unroll
        for (int gg = 0; gg < 16; ++gg) s += red[gg*64 + row*16 + rr];
        tout[(size_t)(m0 + row) * 16 + rr] = s;
    }
}

// ---------- 2. Deep-pipelined GEMM: 4 waves, 128x128 tile, BK=32, 4 LDS stages,
// prefetch distance 3, raw s_barrier (no vmcnt(0) drain) + per-wave partial
// vmcnt waits. Byte-identical to the round-0 gemm (no setprio), which measured
// 136 us / MfmaUtil 21%.
__global__ __launch_bounds__(256) void gemm_kernel(
        const __hip_bfloat16* __restrict__ A,     // [M, K] bf16
        const __hip_bfloat16* __restrict__ B,     // [N, K] bf16 (= W)
        const float* __restrict__ bias,           // [N]
        const float* __restrict__ loraB,          // [N, 16]
        const float* __restrict__ tmat,           // [M, 16]
        float* __restrict__ out) {                // [M, N]
    const int K = IN_F, N = OUT_F;
    __shared__ union alignas(16) {
        struct { __hip_bfloat16 As[4][128*32]; __hip_bfloat16 Bs[4][128*32]; } s; // 64 KB
        float tl[128 * 16];                       // 8 KB, overlaps As[0] only
    } sm;

    int tid  = threadIdx.x;
    int wave = tid >> 6, lane = tid & 63;
    int wm = wave >> 1, wn = wave & 1;            // 2x2 wave grid over 128x128
    int row16 = lane & 15, quad = lane >> 4;
    int m0 = blockIdx.y * 128, n0 = blockIdx.x * 128;

    // DMA mapping (verified R5/R8): lane i -> row rl=i>>2 of 16-row segment,
    // global 16B-chunk cg=(i&3)^((rl>>1)&3); LDS lands at base + lane*16.
    int rl = lane >> 2;
    int cg = (lane & 3) ^ ((rl >> 1) & 3);

    // 4 persistent DMA pointers (A segs wave*2, wave*2+1; same for B)
    const __hip_bfloat16* pA0 = A + (size_t)(m0 + wave*32 + rl) * K + cg*8;
    const __hip_bfloat16* pA1 = pA0 + (size_t)16 * K;
    const __hip_bfloat16* pB0 = B + (size_t)(n0 + wave*32 + rl) * K + cg*8;
    const __hip_bfloat16* pB1 = pB0 + (size_t)16 * K;

    f32x4 acc[4][4];
    #pragma unroll
    for (int i = 0; i < 4; ++i)
        #pragma unroll
        for (int j = 0; j < 4; ++j) acc[i][j] = (f32x4){0.f, 0.f, 0.f, 0.f};

    // stage next slab into stage `buf` (4 loads/wave), advance one slab (64 B)
    #define DMA(buf)                                                              \
        __builtin_amdgcn_global_load_lds((gvoid_t*)pA0, (lvoid_t*)&sm.s.As[buf][(wave*2+0)*512], 16, 0, 0); \
        __builtin_amdgcn_global_load_lds((gvoid_t*)pA1, (lvoid_t*)&sm.s.As[buf][(wave*2+1)*512], 16, 0, 0); \
        __builtin_amdgcn_global_load_lds((gvoid_t*)pB0, (lvoid_t*)&sm.s.Bs[buf][(wave*2+0)*512], 16, 0, 0); \
        __builtin_amdgcn_global_load_lds((gvoid_t*)pB1, (lvoid_t*)&sm.s.Bs[buf][(wave*2+1)*512], 16, 0, 0); \
        pA0 += 32; pA1 += 32; pB0 += 32; pB1 += 32;

    // one 16x16x32 k-step over the slab in stage `buf` (verified R8 math)
    #define COMPUTE(buf)                                                          \
    {                                                                             \
        bf16x8 af[4], bfr[4];                                                     \
        _Pragma("unroll")                                                         \
        for (int mt = 0; mt < 4; ++mt) {                                          \
            int row = wm*64 + mt*16 + row16;                                      \
            af[mt] = *(const bf16x8*)&sm.s.As[buf][row*32 + ((quad ^ ((row>>1)&3)) << 3)]; \
        }                                                                         \
        _Pragma("unroll")                                                         \
        for (int nt = 0; nt < 4; ++nt) {                                          \
            int row = wn*64 + nt*16 + row16;                                      \
            bfr[nt] = *(const bf16x8*)&sm.s.Bs[buf][row*32 + ((quad ^ ((row>>1)&3)) << 3)]; \
        }                                                                         \
        _Pragma("unroll")                                                         \
        for (int mt = 0; mt < 4; ++mt)                                            \
            _Pragma("unroll")                                                     \
            for (int nt = 0; nt < 4; ++nt)                                        \
                acc[mt][nt] = __builtin_amdgcn_mfma_f32_16x16x32_bf16(            \
                    af[mt], bfr[nt], acc[mt][nt], 0, 0, 0);                       \
    }

    // one pipeline step: consume slab in stage p, prefetch into stage (p+3)&3
    // (which holds slab i-1: all waves' reads of it completed before the
    // s_barrier we just passed -> safe to overwrite)
    #define STEP(p)                                                               \
        WAITVM(8);                         /* own slab-i loads retired */         \
        __builtin_amdgcn_s_barrier();      /* all waves ditto => slab i in LDS */ \
        __builtin_amdgcn_sched_barrier(0);                                        \
        COMPUTE(p)                                                                \
        DMA((p+3)&3)

    // prologue: slabs 0,1,2 -> stages 0,1,2 (12 loads/wave outstanding)
    DMA(0)
    DMA(1)
    DMA(2)

    // main: groups u=0..30 consume slabs 4u..4u+3, prefetch 4u+3..4u+6
    for (int u = 0; u < 31; ++u) {
        STEP(0)
        STEP(1)
        STEP(2)
        STEP(3)
    }
    // tail: slabs 124..127 (slab 127 issued at p=0; then drain)
    STEP(0)
    WAITVM(8); __builtin_amdgcn_s_barrier(); __builtin_amdgcn_sched_barrier(0);
    COMPUTE(1)
    WAITVM(4); __builtin_amdgcn_s_barrier(); __builtin_amdgcn_sched_barrier(0);
    COMPUTE(2)
    WAITVM(0); __builtin_amdgcn_s_barrier(); __builtin_amdgcn_sched_barrier(0);
    COMPUTE(3)

    #undef STEP
    #undef COMPUTE
    #undef DMA

    // fused epilogue. tl overlaps As[0] (all stage reads are complete: each
    // wave's last ds_reads finished before its final barrier/MFMA waits; only
    // Bs[3]/As[3] are possibly still being read, and tl is disjoint from them).
    #pragma unroll
    for (int i = 0; i < 2; ++i)
        ((float4*)sm.tl)[tid + i*256] =
            ((const float4*)(tmat + (size_t)m0 * 16))[tid + i*256];
    __syncthreads();

    #pragma unroll
    for (int nt = 0; nt < 4; ++nt) {
        int n = n0 + wn*64 + nt*16 + row16;
        float bn = bias[n];
        const float4* lb = (const float4*)(loraB + (size_t)n * 16);
        float4 b0 = lb[0], b1 = lb[1], b2 = lb[2], b3 = lb[3];
        #pragma unroll
        for (int mt = 0; mt < 4; ++mt) {
            #pragma unroll
            for (int r = 0; r < 4; ++r) {
                int ml = wm*64 + mt*16 + quad*4 + r;
                const float* tm = &sm.tl[ml * 16];
                float dot =
                    tm[0]*b0.x + tm[1]*b0.y + tm[2]*b0.z + tm[3]*b0.w +
                    tm[4]*b1.x + tm[5]*b1.y + tm[6]*b1.z + tm[7]*b1.w +
                    tm[8]*b2.x + tm[9]*b2.y + tm[10]*b2.z + tm[11]*b2.w +
                    tm[12]*b3.x + tm[13]*b3.y + tm[14]*b3.z + tm[15]*b3.w;
                out[(size_t)(m0 + ml) * N + n] = acc[mt][nt][r] + bn + LORA_SCALE * dot;
            }
        }
    }
}

extern "C" void kernel_launch(void* const* d_in, const int* in_sizes, int n_in,
                              void* d_out, int out_size, void* d_ws, size_t ws_size,
                              hipStream_t stream) {
    const float* x      = (const float*)d_in[0];   // [2,1024,4096]
    const int*   qw     = (const int*)d_in[1];     // [8388608] one byte each
    const float* scales = (const float*)d_in[2];   // [262144]
    const float* bias   = (const float*)d_in[3];   // [4096]
    const float* loraA  = (const float*)d_in[4];   // [16,4096]
    const float* loraB  = (const float*)d_in[5];   // [4096,16]
    float* out = (float*)d_out;

    char* ws = (char*)d_ws;
    __hip_bfloat16* Wb = (__hip_bfloat16*)ws;                 // 33,554,432 B
    __hip_bfloat16* Xb = (__hip_bfloat16*)(ws + 33554432);    // 16,777,216 B
    float* tmat        = (float*)(ws + 50331648);             //    131,072 B

    dequant_kernel<<<8192, 256, 0, stream>>>(qw, scales, Wb);
    xcast_kernel<<<4096, 256, 0, stream>>>(x, Xb);
    lora_kernel<<<512, 256, 0, stream>>>(x, loraA, tmat);
    gemm_kernel<<<dim3(32, 16), 256, 0, stream>>>(Xb, Wb, bias, loraB, tmat, out);
}